// Round 12
// baseline (353.437 us; speedup 1.0000x reference)
//
#include <hip/hip_runtime.h>

#define NRAYS 2048
#define NS    128
#define G     128
#define FC    128
#define APPC  27
#define TILE  8
#define MAXP  48
#define R1    351   // compact item rows: 27 feats + 162 sin + 162 cos; W1 row k = r<27 ? r : r+3
#define NB    768   // grid size; MUST equal launch grid

static __device__ __forceinline__ float tri_sample(const float* __restrict__ vol,
                                                   float gx, float gy, float gz) {
  int x0 = (int)gx; x0 = x0 < 0 ? 0 : (x0 > G - 2 ? G - 2 : x0);
  int y0 = (int)gy; y0 = y0 < 0 ? 0 : (y0 > G - 2 ? G - 2 : y0);
  int z0 = (int)gz; z0 = z0 < 0 ? 0 : (z0 > G - 2 ? G - 2 : z0);
  float fx = gx - (float)x0;
  float fy = gy - (float)y0;
  float fz = gz - (float)z0;
  const float* p = vol + ((z0 * G + y0) * G + x0);
  float v000 = p[0], v001 = p[1];
  float v010 = p[G], v011 = p[G + 1];
  const float* q = p + G * G;
  float v100 = q[0], v101 = q[1];
  float v110 = q[G], v111 = q[G + 1];
  float c00 = v000 + (v001 - v000) * fx;
  float c01 = v010 + (v011 - v010) * fx;
  float c10 = v100 + (v101 - v100) * fx;
  float c11 = v110 + (v111 - v110) * fx;
  float c0  = c00 + (c01 - c00) * fy;
  float c1  = c10 + (c11 - c10) * fy;
  return c0 + (c1 - c0) * fz;
}

// softplus(x) for x <= ~-5: log1p(e^x) = e^x - e^x^2/2; abs error < 1e-8
static __device__ __forceinline__ float sample_alpha(const float* __restrict__ dgrid,
                                                     float ox, float oy, float oz,
                                                     float dx, float dy, float dz,
                                                     int s, bool& inb) {
  const float t  = 2.0f + (4.0f / 127.0f) * (float)s;
  const float px = (ox + dx * t) * (2.0f / 3.0f);
  const float py = (oy + dy * t) * (2.0f / 3.0f);
  const float pz = (oz + dz * t) * (2.0f / 3.0f);
  inb = (fabsf(px) <= 1.0f) && (fabsf(py) <= 1.0f) && (fabsf(pz) <= 1.0f);
  float sf = 0.0f;
  if (inb)
    sf = tri_sample(dgrid, (px + 1.0f) * 63.5f, (py + 1.0f) * 63.5f, (pz + 1.0f) * 63.5f);
  const float y  = __expf(sf - 10.0f);
  const float sp = y - 0.5f * y * y;
  return 1.0f - __expf(-sp * 0.78125f);
}

struct SBase {
  float in[39][8];      // rows 0-2 vd; 3-20 sin(vd); 21-38 cos(vd)
  float h1[FC][12];
  float h2[FC][12];
  float bc[FC], ps[FC];
};
struct SItems {
  int   pfx[NRAYS + 1];   // 8196 B
  int   wt[4];
  float inT[R1][TILE];    // 11232 B; tail reused as h2 [128][12]
  float hT[FC][12];       // 6144 B
  int   rayid[TILE];
  float jw[TILE], gx[TILE], gy[TILE], gz[TILE];
  int   vld[TILE];
};
union SMem { SBase base; SItems items; };

__global__ __launch_bounds__(256, 3) void k_all(
    const float* __restrict__ rays_o, const float* __restrict__ rays_d,
    const float* __restrict__ dgrid, const float* __restrict__ agrid,
    const float* __restrict__ W1, const float* __restrict__ W2,
    const float* __restrict__ W3, const float* __restrict__ b1,
    const float* __restrict__ b2, const float* __restrict__ b3,
    float* __restrict__ out, float* __restrict__ g_dir,
    float* __restrict__ g_woob, float* __restrict__ g_hbase,
    float* __restrict__ g_rgboob, unsigned char* __restrict__ g_cnt8,
    unsigned char* __restrict__ g_sidx, float* __restrict__ g_w,
    unsigned int* __restrict__ g_bar) {
  const int bid = blockIdx.x;
  const int tid = threadIdx.x;
  __shared__ SMem sm;

  unsigned int* cnt  = g_bar;
  unsigned int* flag = g_bar + 16;   // separate cache line-ish

  // barrier init (poison-immune: protocol always starts from flag!=1/2)
  if (bid == 0 && tid == 0) {
    __hip_atomic_store(cnt, 0u, __ATOMIC_RELAXED, __HIP_MEMORY_SCOPE_AGENT);
    __hip_atomic_store(flag, 1u, __ATOMIC_RELEASE, __HIP_MEMORY_SCOPE_AGENT);
  }

  // =================== PHASE 1 ===================
  if (bid < 512) {
    // ---- prep: one wave per ray; fixed per-ray slots, no atomics ----
    const int ray  = bid * 4 + (tid >> 6);
    const int lane = tid & 63;

    const float rdx = rays_d[ray * 3 + 0], rdy = rays_d[ray * 3 + 1], rdz = rays_d[ray * 3 + 2];
    const float inv = rsqrtf(rdx * rdx + rdy * rdy + rdz * rdz);
    const float dx = rdx * inv, dy = rdy * inv, dz = rdz * inv;
    const float ox = rays_o[ray * 3 + 0], oy = rays_o[ray * 3 + 1], oz = rays_o[ray * 3 + 2];
    if (lane == 0) {
      g_dir[ray * 3 + 0] = dx; g_dir[ray * 3 + 1] = dy; g_dir[ray * 3 + 2] = dz;
    }

    const int s0 = lane * 2, s1 = s0 + 1;
    bool in0, in1;
    const float al0 = sample_alpha(dgrid, ox, oy, oz, dx, dy, dz, s0, in0);
    const float al1 = sample_alpha(dgrid, ox, oy, oz, dx, dy, dz, s1, in1);

    const float p0 = 1.0f - al0 + 1e-10f;
    const float p1 = 1.0f - al1 + 1e-10f;
    float incl = p0 * p1;
#pragma unroll
    for (int off = 1; off < 64; off <<= 1) {
      float v = __shfl_up(incl, off);
      if (lane >= off) incl *= v;
    }
    float excl = __shfl_up(incl, 1);
    if (lane == 0) excl = 1.0f;
    const float w0 = al0 * excl;
    const float w1 = al1 * excl * p0;

    float acc  = w0 + w1;
    float woob = (in0 ? 0.0f : w0) + (in1 ? 0.0f : w1);
#pragma unroll
    for (int off = 32; off > 0; off >>= 1) {
      acc  += __shfl_xor(acc, off);
      woob += __shfl_xor(woob, off);
    }

    const unsigned long long m0 = __ballot(in0);
    const unsigned long long m1 = __ballot(in1);
    const int n_in = (int)__popcll(m0) + (int)__popcll(m1);

    if (lane == 0) {
      g_woob[ray] = woob;
      g_cnt8[ray] = (unsigned char)((n_in > MAXP) ? MAXP : n_in);
    }
    if (lane < 3) out[ray * 3 + lane] = 1.0f - acc;   // phase 2 atomically adds onto this

    const unsigned long long low = (1ull << lane) - 1ull;
    const int r0 = (int)__popcll(m0 & low) + (int)__popcll(m1 & low);
    if (in0 && r0 < MAXP) {
      g_sidx[ray * MAXP + r0] = (unsigned char)s0;
      g_w[ray * MAXP + r0]    = w0;
    }
    if (in1) {
      const int r1 = r0 + (in0 ? 1 : 0);
      if (r1 < MAXP) {
        g_sidx[ray * MAXP + r1] = (unsigned char)s1;
        g_w[ray * MAXP + r1]    = w1;
      }
    }
  } else {
    // ---- base: 8 rays per block (256 blocks) -> g_hbase + g_rgboob ----
    const int r0 = (bid - 512) * 8;
    if (tid < 24) {
      const int j = tid & 7, d = tid >> 3;
      const float rdx = rays_d[(r0 + j) * 3 + 0], rdy = rays_d[(r0 + j) * 3 + 1],
                  rdz = rays_d[(r0 + j) * 3 + 2];
      const float inv = rsqrtf(rdx * rdx + rdy * rdy + rdz * rdz);
      sm.base.in[d][j] = (d == 0) ? rdx * inv : ((d == 1) ? rdy * inv : rdz * inv);
    }
    {  // cos(0)-block column sums, two interleaved halves (no dep on s_in)
      const int nrn = tid & 127, h = tid >> 7;
      float v = 0.0f;
#pragma unroll 9
      for (int k = 192 + h; k < 354; k += 2) v += W1[k * FC + nrn];
      if (h) sm.base.ps[nrn] = v; else sm.base.bc[nrn] = v;
    }
    __syncthreads();
    for (int a = tid; a < 18 * 8; a += 256) {
      const int j = a & 7, idx = a >> 3, d = idx / 6, f = idx % 6;
      float sn, cs; __sincosf(sm.base.in[d][j] * (float)(1 << f), &sn, &cs);
      sm.base.in[3 + idx][j]  = sn;
      sm.base.in[21 + idx][j] = cs;
    }
    __syncthreads();

    const int nrn = tid & 127;
    const int j0  = (tid >> 7) * 4;

    float a1[4];
    {
      const float bb = b1[nrn];
#pragma unroll
      for (int i = 0; i < 4; ++i) a1[i] = bb;
    }
#pragma unroll
    for (int r = 0; r < 39; ++r) {
      const int k = (r < 3) ? (27 + r) : (351 + r);
      const float wv = W1[k * FC + nrn];
      const float4 v0 = *(const float4*)&sm.base.in[r][j0];
      a1[0] = fmaf(v0.x, wv, a1[0]); a1[1] = fmaf(v0.y, wv, a1[1]);
      a1[2] = fmaf(v0.z, wv, a1[2]); a1[3] = fmaf(v0.w, wv, a1[3]);
    }
    const float bcv = sm.base.bc[nrn] + sm.base.ps[nrn];
#pragma unroll
    for (int i = 0; i < 4; ++i) {
      g_hbase[(size_t)(r0 + j0 + i) * FC + nrn] = a1[i];
      sm.base.h1[nrn][j0 + i] = fmaxf(a1[i] + bcv, 0.0f);
    }
    __syncthreads();

    float a2[4];
    {
      const float bb = b2[nrn];
#pragma unroll
      for (int i = 0; i < 4; ++i) a2[i] = bb;
    }
#pragma unroll 4
    for (int k = 0; k < FC; ++k) {
      const float wv = W2[k * FC + nrn];
      const float4 u0 = *(const float4*)&sm.base.h1[k][j0];
      a2[0] = fmaf(u0.x, wv, a2[0]); a2[1] = fmaf(u0.y, wv, a2[1]);
      a2[2] = fmaf(u0.z, wv, a2[2]); a2[3] = fmaf(u0.w, wv, a2[3]);
    }
#pragma unroll
    for (int i = 0; i < 4; ++i) sm.base.h2[nrn][j0 + i] = fmaxf(a2[i], 0.0f);
    __syncthreads();

    if (tid < 24) {
      const int j = tid / 3, c = tid - j * 3;
      float a3 = b3[c];
#pragma unroll 8
      for (int k = 0; k < FC; ++k)
        a3 = fmaf(sm.base.h2[k][j], W3[k * 3 + c], a3);
      g_rgboob[(r0 + j) * 3 + c] = 1.0f / (1.0f + __expf(-a3));
    }
  }

  // =================== software grid barrier (self-resetting, poison-immune) ===================
  __threadfence();     // release this thread's phase-1 stores device-wide
  __syncthreads();
  if (tid == 0) {
    int guard = 2000000;
    while (__hip_atomic_load(flag, __ATOMIC_ACQUIRE, __HIP_MEMORY_SCOPE_AGENT) != 1u && --guard)
      __builtin_amdgcn_s_sleep(2);
    const unsigned int old = atomicAdd(cnt, 1u);
    if (old == NB - 1u)
      __hip_atomic_store(flag, 2u, __ATOMIC_RELEASE, __HIP_MEMORY_SCOPE_AGENT);
    guard = 2000000;
    while (__hip_atomic_load(flag, __ATOMIC_ACQUIRE, __HIP_MEMORY_SCOPE_AGENT) != 2u && --guard)
      __builtin_amdgcn_s_sleep(2);
    const unsigned int old2 = atomicSub(cnt, 1u);
    if (old2 == 1u)
      __hip_atomic_store(flag, 0u, __ATOMIC_RELEASE, __HIP_MEMORY_SCOPE_AGENT);
  }
  __syncthreads();

  // =================== PHASE 2: prefix + OOB composite + item MLP ===================
  {
    const int b0 = tid * 8;
    const uint2 cc = *(const uint2*)&g_cnt8[b0];
    int c8[8];
#pragma unroll
    for (int i = 0; i < 4; ++i) c8[i]     = (int)((cc.x >> (8 * i)) & 0xff);
#pragma unroll
    for (int i = 0; i < 4; ++i) c8[4 + i] = (int)((cc.y >> (8 * i)) & 0xff);
    int ex[8], run = 0;
#pragma unroll
    for (int i = 0; i < 8; ++i) { ex[i] = run; run += c8[i]; }
    int inclv = run;
    const int lane = tid & 63;
#pragma unroll
    for (int off = 1; off < 64; off <<= 1) {
      int v = __shfl_up(inclv, off);
      if (lane >= off) inclv += v;
    }
    if (lane == 63) sm.items.wt[tid >> 6] = inclv;
    __syncthreads();
    int woff = 0;
    const int wq = tid >> 6;
    if (wq > 0) woff += sm.items.wt[0];
    if (wq > 1) woff += sm.items.wt[1];
    if (wq > 2) woff += sm.items.wt[2];
    const int tbase = woff + inclv - run;
#pragma unroll
    for (int i = 0; i < 8; ++i) sm.items.pfx[b0 + i] = tbase + ex[i];
    if (tid == 255) sm.items.pfx[NRAYS] = tbase + run;
  }
  __syncthreads();
  const int total  = sm.items.pfx[NRAYS];
  const int ntiles = 8 + ((total + TILE - 1) >> 3);

  for (int tile = bid; tile < ntiles; tile += NB) {
    if (tile < 8) {   // OOB composite (block-uniform branch)
      const int ray = tile * 256 + tid;
      const float wv = g_woob[ray];
#pragma unroll
      for (int c = 0; c < 3; ++c)
        atomicAdd(&out[ray * 3 + c], wv * g_rgboob[ray * 3 + c]);
      continue;
    }
    const int it = tile - 8;

    if (tid < TILE) {
      const int gi  = it * TILE + tid;
      const int vld = gi < total;
      int ray = 0, s = 0;
      float wj = 0.0f;
      if (vld) {
        int lo = 0, hi = NRAYS - 1;
        while (lo < hi) {
          const int mid = (lo + hi + 1) >> 1;
          if (sm.items.pfx[mid] <= gi) lo = mid; else hi = mid - 1;
        }
        ray = lo;
        const int slot = gi - sm.items.pfx[ray];
        s  = g_sidx[ray * MAXP + slot];
        wj = g_w[ray * MAXP + slot];
      }
      sm.items.rayid[tid] = ray;
      sm.items.vld[tid]   = vld;
      sm.items.jw[tid]    = wj;
      const float dxx = g_dir[ray * 3 + 0], dyy = g_dir[ray * 3 + 1], dzz = g_dir[ray * 3 + 2];
      const float t = 2.0f + (4.0f / 127.0f) * (float)s;
      sm.items.gx[tid] = ((rays_o[ray * 3 + 0] + dxx * t) * (2.0f / 3.0f) + 1.0f) * 63.5f;
      sm.items.gy[tid] = ((rays_o[ray * 3 + 1] + dyy * t) * (2.0f / 3.0f) + 1.0f) * 63.5f;
      sm.items.gz[tid] = ((rays_o[ray * 3 + 2] + dzz * t) * (2.0f / 3.0f) + 1.0f) * 63.5f;
    }
    __syncthreads();

    // fused gather + PE: thread (c,j) samples channel c then writes its 6 sin/cos pairs
    if (tid < APPC * TILE) {   // 216 threads
      const int j = tid & (TILE - 1), c = tid >> 3;
      const float v = sm.items.vld[j]
          ? tri_sample(agrid + (size_t)c * G * G * G, sm.items.gx[j], sm.items.gy[j], sm.items.gz[j])
          : 0.0f;
      sm.items.inT[c][j] = v;
#pragma unroll
      for (int f = 0; f < 6; ++f) {
        float sn, cs; __sincosf(v * (float)(1 << f), &sn, &cs);
        sm.items.inT[27 + c * 6 + f][j]  = sn;
        sm.items.inT[189 + c * 6 + f][j] = cs;
      }
    }
    __syncthreads();

    const int nrn = tid & 127;
    const int j0  = (tid >> 7) * 4;

    float a1[4];
#pragma unroll
    for (int i = 0; i < 4; ++i)
      a1[i] = g_hbase[(size_t)sm.items.rayid[j0 + i] * FC + nrn];

    const float* w1p = W1 + nrn;
#pragma unroll 9
    for (int r = 0; r < 27; ++r) {
      const float wv = w1p[r * FC];
      const float4 v0 = *(const float4*)&sm.items.inT[r][j0];
      a1[0] = fmaf(v0.x, wv, a1[0]); a1[1] = fmaf(v0.y, wv, a1[1]);
      a1[2] = fmaf(v0.z, wv, a1[2]); a1[3] = fmaf(v0.w, wv, a1[3]);
    }
#pragma unroll 8
    for (int r = 27; r < R1; ++r) {
      const float wv = w1p[(r + 3) * FC];
      const float4 v0 = *(const float4*)&sm.items.inT[r][j0];
      a1[0] = fmaf(v0.x, wv, a1[0]); a1[1] = fmaf(v0.y, wv, a1[1]);
      a1[2] = fmaf(v0.z, wv, a1[2]); a1[3] = fmaf(v0.w, wv, a1[3]);
    }
#pragma unroll
    for (int i = 0; i < 4; ++i) sm.items.hT[nrn][j0 + i] = fmaxf(a1[i], 0.0f);
    __syncthreads();

    float a2[4];
    {
      const float bb = b2[nrn];
#pragma unroll
      for (int i = 0; i < 4; ++i) a2[i] = bb;
    }
#pragma unroll 4
    for (int k = 0; k < FC; ++k) {
      const float wv = W2[k * FC + nrn];
      const float4 u0 = *(const float4*)&sm.items.hT[k][j0];
      a2[0] = fmaf(u0.x, wv, a2[0]); a2[1] = fmaf(u0.y, wv, a2[1]);
      a2[2] = fmaf(u0.z, wv, a2[2]); a2[3] = fmaf(u0.w, wv, a2[3]);
    }
    float* s_h2 = &sm.items.inT[0][0];  // reuse as [128][12]; inT reads done pre-barrier
#pragma unroll
    for (int i = 0; i < 4; ++i) s_h2[nrn * 12 + j0 + i] = fmaxf(a2[i], 0.0f);
    __syncthreads();

    if (tid < 3 * TILE) {
      const int j = tid / 3, c = tid - j * 3;
      if (sm.items.vld[j] && sm.items.jw[j] != 0.0f) {
        float a3 = b3[c];
#pragma unroll 8
        for (int k = 0; k < FC; ++k)
          a3 = fmaf(s_h2[k * 12 + j], W3[k * 3 + c], a3);
        const float rgb = 1.0f / (1.0f + __expf(-a3));
        atomicAdd(&out[sm.items.rayid[j] * 3 + c], sm.items.jw[j] * rgb);
      }
    }
    __syncthreads();
  }
}

extern "C" void kernel_launch(void* const* d_in, const int* in_sizes, int n_in,
                              void* d_out, int out_size, void* d_ws, size_t ws_size,
                              hipStream_t stream) {
  const float* rays_o = (const float*)d_in[0];
  const float* rays_d = (const float*)d_in[1];
  const float* dgrid  = (const float*)d_in[2];
  const float* agrid  = (const float*)d_in[3];
  const float* W1     = (const float*)d_in[4];
  const float* b1     = (const float*)d_in[5];
  const float* W2     = (const float*)d_in[6];
  const float* b2     = (const float*)d_in[7];
  const float* W3     = (const float*)d_in[8];
  const float* b3     = (const float*)d_in[9];
  float* out = (float*)d_out;

  char* ws = (char*)d_ws;
  unsigned int*  g_bar    = (unsigned int*)(ws);           // 128 B (cnt @0, flag @64)
  float*         g_dir    = (float*)(ws + 1024);           // 24 KB
  float*         g_woob   = (float*)(ws + 25600);          // 8 KB
  float*         g_rgboob = (float*)(ws + 33792);          // 24 KB
  unsigned char* g_cnt8   = (unsigned char*)(ws + 58368);  // 2 KB
  float*         g_hbase  = (float*)(ws + 65536);          // 1 MB
  float*         g_w      = (float*)(ws + 65536 + 1048576);                   // 384 KB
  unsigned char* g_sidx   = (unsigned char*)(ws + 65536 + 1048576 + 393216);  // 96 KB

  hipLaunchKernelGGL(k_all, dim3(NB), dim3(256), 0, stream,
                     rays_o, rays_d, dgrid, agrid, W1, W2, W3, b1, b2, b3,
                     out, g_dir, g_woob, g_hbase, g_rgboob, g_cnt8, g_sidx, g_w, g_bar);
}

// Round 13
// 65.997 us; speedup vs baseline: 5.3553x; 5.3553x over previous
//
#include <hip/hip_runtime.h>

#define NRAYS 2048
#define NS    128
#define G     128
#define FC    128
#define APPC  27
#define TILE  8
#define MAXP  48
#define NB2   768   // K2 grid

static __device__ __forceinline__ float tri_sample(const float* __restrict__ vol,
                                                   float gx, float gy, float gz) {
  int x0 = (int)gx; x0 = x0 < 0 ? 0 : (x0 > G - 2 ? G - 2 : x0);
  int y0 = (int)gy; y0 = y0 < 0 ? 0 : (y0 > G - 2 ? G - 2 : y0);
  int z0 = (int)gz; z0 = z0 < 0 ? 0 : (z0 > G - 2 ? G - 2 : z0);
  float fx = gx - (float)x0;
  float fy = gy - (float)y0;
  float fz = gz - (float)z0;
  const float* p = vol + ((z0 * G + y0) * G + x0);
  float v000 = p[0], v001 = p[1];
  float v010 = p[G], v011 = p[G + 1];
  const float* q = p + G * G;
  float v100 = q[0], v101 = q[1];
  float v110 = q[G], v111 = q[G + 1];
  float c00 = v000 + (v001 - v000) * fx;
  float c01 = v010 + (v011 - v010) * fx;
  float c10 = v100 + (v101 - v100) * fx;
  float c11 = v110 + (v111 - v110) * fx;
  float c0  = c00 + (c01 - c00) * fy;
  float c1  = c10 + (c11 - c10) * fy;
  return c0 + (c1 - c0) * fz;
}

// softplus(x) for x <= ~-5: log1p(e^x) = e^x - e^x^2/2; abs error < 1e-8
static __device__ __forceinline__ float sample_alpha(const float* __restrict__ dgrid,
                                                     float ox, float oy, float oz,
                                                     float dx, float dy, float dz,
                                                     int s, bool& inb) {
  const float t  = 2.0f + (4.0f / 127.0f) * (float)s;
  const float px = (ox + dx * t) * (2.0f / 3.0f);
  const float py = (oy + dy * t) * (2.0f / 3.0f);
  const float pz = (oz + dz * t) * (2.0f / 3.0f);
  inb = (fabsf(px) <= 1.0f) && (fabsf(py) <= 1.0f) && (fabsf(pz) <= 1.0f);
  float sf = 0.0f;
  if (inb)
    sf = tri_sample(dgrid, (px + 1.0f) * 63.5f, (py + 1.0f) * 63.5f, (pz + 1.0f) * 63.5f);
  const float y  = __expf(sf - 10.0f);
  const float sp = y - 0.5f * y * y;
  return 1.0f - __expf(-sp * 0.78125f);
}

// ---------------- K1: prep + in-block OOB MLP; one block per 4 rays ----------------
__global__ __launch_bounds__(256) void k_prep(
    const float* __restrict__ rays_o, const float* __restrict__ rays_d,
    const float* __restrict__ dgrid,
    const float* __restrict__ W1, const float* __restrict__ W2,
    const float* __restrict__ W3, const float* __restrict__ b1,
    const float* __restrict__ b2, const float* __restrict__ b3,
    float* __restrict__ out, float* __restrict__ g_dir,
    unsigned char* __restrict__ g_cnt8,
    unsigned char* __restrict__ g_sidx, float* __restrict__ g_w) {
  const int bid = blockIdx.x;
  const int tid = threadIdx.x;

  __shared__ float s_dir[3][4];
  __shared__ float s_woob[4], s_acc[4];
  __shared__ float s_bc[FC], s_ps[FC];
  __shared__ float s_in[39][4];        // rows 0-2 vd; 3-20 sin(vd); 21-38 cos(vd)
  __shared__ float s_p[2][FC][4];      // split-K partials (reused layer1/layer2)
  __shared__ float s_h1[FC][4];
  __shared__ float s_h2[FC][4];
  __shared__ float s_p3[12][2];

  // ---- phase A: per-wave ray prep (identical math to proven R9 prep) ----
  {
    const int w    = tid >> 6;
    const int lane = tid & 63;
    const int ray  = bid * 4 + w;

    const float rdx = rays_d[ray * 3 + 0], rdy = rays_d[ray * 3 + 1], rdz = rays_d[ray * 3 + 2];
    const float inv = rsqrtf(rdx * rdx + rdy * rdy + rdz * rdz);
    const float dx = rdx * inv, dy = rdy * inv, dz = rdz * inv;
    const float ox = rays_o[ray * 3 + 0], oy = rays_o[ray * 3 + 1], oz = rays_o[ray * 3 + 2];
    if (lane == 0) {
      g_dir[ray * 3 + 0] = dx; g_dir[ray * 3 + 1] = dy; g_dir[ray * 3 + 2] = dz;
      s_dir[0][w] = dx; s_dir[1][w] = dy; s_dir[2][w] = dz;
    }

    const int s0 = lane * 2, s1 = s0 + 1;
    bool in0, in1;
    const float al0 = sample_alpha(dgrid, ox, oy, oz, dx, dy, dz, s0, in0);
    const float al1 = sample_alpha(dgrid, ox, oy, oz, dx, dy, dz, s1, in1);

    const float p0 = 1.0f - al0 + 1e-10f;
    const float p1 = 1.0f - al1 + 1e-10f;
    float incl = p0 * p1;
#pragma unroll
    for (int off = 1; off < 64; off <<= 1) {
      float v = __shfl_up(incl, off);
      if (lane >= off) incl *= v;
    }
    float excl = __shfl_up(incl, 1);
    if (lane == 0) excl = 1.0f;
    const float w0 = al0 * excl;
    const float w1 = al1 * excl * p0;

    float acc  = w0 + w1;
    float woob = (in0 ? 0.0f : w0) + (in1 ? 0.0f : w1);
#pragma unroll
    for (int off = 32; off > 0; off >>= 1) {
      acc  += __shfl_xor(acc, off);
      woob += __shfl_xor(woob, off);
    }

    const unsigned long long m0 = __ballot(in0);
    const unsigned long long m1 = __ballot(in1);
    const int n_in = (int)__popcll(m0) + (int)__popcll(m1);

    if (lane == 0) {
      s_woob[w] = woob;
      s_acc[w]  = acc;
      g_cnt8[ray] = (unsigned char)((n_in > MAXP) ? MAXP : n_in);
    }

    const unsigned long long low = (1ull << lane) - 1ull;
    const int r0 = (int)__popcll(m0 & low) + (int)__popcll(m1 & low);
    if (in0 && r0 < MAXP) {
      g_sidx[ray * MAXP + r0] = (unsigned char)s0;
      g_w[ray * MAXP + r0]    = w0;
    }
    if (in1) {
      const int r1 = r0 + (in0 ? 1 : 0);
      if (r1 < MAXP) {
        g_sidx[ray * MAXP + r1] = (unsigned char)s1;
        g_w[ray * MAXP + r1]    = w1;
      }
    }
  }

  // ---- phase B: cos(0)-block column sums (interleaved halves) ----
  {
    const int nrn = tid & 127, h = tid >> 7;
    float v = 0.0f;
#pragma unroll 9
    for (int k = 192 + h; k < 354; k += 2) v += W1[k * FC + nrn];
    if (h) s_ps[nrn] = v; else s_bc[nrn] = v;
  }
  __syncthreads();

  // ---- phase C: vd rows + PE(vd) for the 4 rays ----
  if (tid < 12) {
    const int j = tid & 3, d = tid >> 2;
    s_in[d][j] = s_dir[d][j];
  }
  for (int a = tid; a < 72; a += 256) {
    const int j = a & 3, idx = a >> 2, d = idx / 6, f = idx % 6;
    float sn, cs; __sincosf(s_dir[d][j] * (float)(1 << f), &sn, &cs);
    s_in[3 + idx][j]  = sn;
    s_in[21 + idx][j] = cs;
  }
  __syncthreads();

  const int nrn = tid & 127;
  const int h   = tid >> 7;

  // ---- layer 1, split-K: h=0 rows 0-19 (+b1), h=1 rows 20-38 (+bc) ----
  {
    float a1[4];
    const float init = h ? (s_bc[nrn] + s_ps[nrn]) : b1[nrn];
#pragma unroll
    for (int i = 0; i < 4; ++i) a1[i] = h ? init : init;
#pragma unroll
    for (int i = 0; i < 4; ++i) a1[i] = init;
    const int rlo = h ? 20 : 0, rhi = h ? 39 : 20;
    for (int r = rlo; r < rhi; ++r) {
      const int k = (r < 3) ? (27 + r) : (351 + r);
      const float wv = W1[k * FC + nrn];
      const float4 v0 = *(const float4*)&s_in[r][0];
      a1[0] = fmaf(v0.x, wv, a1[0]); a1[1] = fmaf(v0.y, wv, a1[1]);
      a1[2] = fmaf(v0.z, wv, a1[2]); a1[3] = fmaf(v0.w, wv, a1[3]);
    }
    *(float4*)&s_p[h][nrn][0] = make_float4(a1[0], a1[1], a1[2], a1[3]);
  }
  __syncthreads();
  if (tid < FC) {
    const float4 q0 = *(const float4*)&s_p[0][tid][0];
    const float4 q1 = *(const float4*)&s_p[1][tid][0];
    s_h1[tid][0] = fmaxf(q0.x + q1.x, 0.0f);
    s_h1[tid][1] = fmaxf(q0.y + q1.y, 0.0f);
    s_h1[tid][2] = fmaxf(q0.z + q1.z, 0.0f);
    s_h1[tid][3] = fmaxf(q0.w + q1.w, 0.0f);
  }
  __syncthreads();

  // ---- layer 2, split-K halves of 64 ----
  {
    float a2[4] = {0.0f, 0.0f, 0.0f, 0.0f};
    const int k0 = h * 64;
#pragma unroll 4
    for (int kk = 0; kk < 64; ++kk) {
      const int k = k0 + kk;
      const float wv = W2[k * FC + nrn];
      const float4 u0 = *(const float4*)&s_h1[k][0];
      a2[0] = fmaf(u0.x, wv, a2[0]); a2[1] = fmaf(u0.y, wv, a2[1]);
      a2[2] = fmaf(u0.z, wv, a2[2]); a2[3] = fmaf(u0.w, wv, a2[3]);
    }
    *(float4*)&s_p[h][nrn][0] = make_float4(a2[0], a2[1], a2[2], a2[3]);
  }
  __syncthreads();
  if (tid < FC) {
    const float bb = b2[tid];
    const float4 q0 = *(const float4*)&s_p[0][tid][0];
    const float4 q1 = *(const float4*)&s_p[1][tid][0];
    s_h2[tid][0] = fmaxf(bb + q0.x + q1.x, 0.0f);
    s_h2[tid][1] = fmaxf(bb + q0.y + q1.y, 0.0f);
    s_h2[tid][2] = fmaxf(bb + q0.z + q1.z, 0.0f);
    s_h2[tid][3] = fmaxf(bb + q0.w + q1.w, 0.0f);
  }
  __syncthreads();

  // ---- layer 3 (12 outputs x 2 K-halves) + final OOB-only composite ----
  if (tid < 24) {
    const int q = tid >> 1, hf = tid & 1;
    const int j = q / 3, c = q - j * 3;
    float a3 = 0.0f;
#pragma unroll 8
    for (int kk = 0; kk < 64; ++kk) {
      const int k = hf * 64 + kk;
      a3 = fmaf(s_h2[k][j], W3[k * 3 + c], a3);
    }
    s_p3[q][hf] = a3;
  }
  __syncthreads();
  if (tid < 12) {
    const int j = tid / 3, c = tid - j * 3;
    const float a3  = b3[c] + s_p3[tid][0] + s_p3[tid][1];
    const float rgb = 1.0f / (1.0f + __expf(-a3));
    out[(bid * 4 + j) * 3 + c] = s_woob[j] * rgb + (1.0f - s_acc[j]);
  }
}

// ---------------- K2: prefix + item MLP (full 390-row layer 1, no hbase) ----------------
__global__ __launch_bounds__(256) void k_items(const float* __restrict__ rays_o,
                                               const float* __restrict__ g_dir,
                                               const float* __restrict__ agrid,
                                               const float* __restrict__ W1,
                                               const float* __restrict__ W2,
                                               const float* __restrict__ W3,
                                               const float* __restrict__ b1,
                                               const float* __restrict__ b2,
                                               const float* __restrict__ b3,
                                               const unsigned char* __restrict__ g_cnt8,
                                               const unsigned char* __restrict__ g_sidx,
                                               const float* __restrict__ g_w,
                                               float* __restrict__ out) {
  const int tid = threadIdx.x;
  __shared__ int   s_pfx[NRAYS + 1];
  __shared__ int   s_wt[4];
  __shared__ float s_inT[390][TILE];  // rows: 0-26 feats, 27-188 sin, 189-350 cos,
                                      //       351-353 vd, 354-371 sin(vd), 372-389 cos(vd)
  __shared__ float s_hT[FC][12];
  __shared__ int   s_rayid[TILE];
  __shared__ float s_jw[TILE], s_gx[TILE], s_gy[TILE], s_gz[TILE];
  __shared__ int   s_vld[TILE];

  // ---- exclusive prefix sum of per-ray item counts (uchar, exact ints) ----
  {
    const int b0 = tid * 8;
    const uint2 cc = *(const uint2*)&g_cnt8[b0];
    int c8[8];
#pragma unroll
    for (int i = 0; i < 4; ++i) c8[i]     = (int)((cc.x >> (8 * i)) & 0xff);
#pragma unroll
    for (int i = 0; i < 4; ++i) c8[4 + i] = (int)((cc.y >> (8 * i)) & 0xff);
    int ex[8], run = 0;
#pragma unroll
    for (int i = 0; i < 8; ++i) { ex[i] = run; run += c8[i]; }
    int inclv = run;
    const int lane = tid & 63;
#pragma unroll
    for (int off = 1; off < 64; off <<= 1) {
      int v = __shfl_up(inclv, off);
      if (lane >= off) inclv += v;
    }
    if (lane == 63) s_wt[tid >> 6] = inclv;
    __syncthreads();
    int woff = 0;
    const int wq = tid >> 6;
    if (wq > 0) woff += s_wt[0];
    if (wq > 1) woff += s_wt[1];
    if (wq > 2) woff += s_wt[2];
    const int tbase = woff + inclv - run;
#pragma unroll
    for (int i = 0; i < 8; ++i) s_pfx[b0 + i] = tbase + ex[i];
    if (tid == 255) s_pfx[NRAYS] = tbase + run;
  }
  __syncthreads();
  const int total  = s_pfx[NRAYS];
  const int ntiles = (total + TILE - 1) >> 3;

  for (int tile = blockIdx.x; tile < ntiles; tile += NB2) {
    if (tid < TILE) {
      const int gi  = tile * TILE + tid;
      const int vld = gi < total;
      int ray = 0, s = 0;
      float wj = 0.0f;
      if (vld) {
        int lo = 0, hi = NRAYS - 1;
        while (lo < hi) {
          const int mid = (lo + hi + 1) >> 1;
          if (s_pfx[mid] <= gi) lo = mid; else hi = mid - 1;
        }
        ray = lo;
        const int slot = gi - s_pfx[ray];
        s  = g_sidx[ray * MAXP + slot];
        wj = g_w[ray * MAXP + slot];
      }
      s_rayid[tid] = ray;
      s_vld[tid]   = vld;
      s_jw[tid]    = wj;
      const float dxx = g_dir[ray * 3 + 0], dyy = g_dir[ray * 3 + 1], dzz = g_dir[ray * 3 + 2];
      const float t = 2.0f + (4.0f / 127.0f) * (float)s;
      s_gx[tid] = ((rays_o[ray * 3 + 0] + dxx * t) * (2.0f / 3.0f) + 1.0f) * 63.5f;
      s_gy[tid] = ((rays_o[ray * 3 + 1] + dyy * t) * (2.0f / 3.0f) + 1.0f) * 63.5f;
      s_gz[tid] = ((rays_o[ray * 3 + 2] + dzz * t) * (2.0f / 3.0f) + 1.0f) * 63.5f;
    }
    __syncthreads();

    if (tid < APPC * TILE) {   // 216 threads: feature gather
      const int j = tid & (TILE - 1), c = tid >> 3;
      s_inT[c][j] = s_vld[j]
                        ? tri_sample(agrid + (size_t)c * G * G * G, s_gx[j], s_gy[j], s_gz[j])
                        : 0.0f;
    } else {                   // 40 threads: vd rows + PE(vd) rows per item
      for (int a = tid - 216; a < 24; a += 40) {
        const int j = a & 7, d = a >> 3;
        s_inT[351 + d][j] = g_dir[s_rayid[j] * 3 + d];
      }
      for (int a = tid - 216; a < 144; a += 40) {
        const int j = a & 7, idx = a >> 3;
        const int d = idx / 6, f = idx % 6;
        const float dv = g_dir[s_rayid[j] * 3 + d];
        float sn, cs; __sincosf(dv * (float)(1 << f), &sn, &cs);
        s_inT[354 + idx][j] = sn;
        s_inT[372 + idx][j] = cs;
      }
    }
    __syncthreads();

    for (int a = tid; a < 162 * TILE; a += 256) {   // PE(feats)
      const int j = a & (TILE - 1), idx = a >> 3;
      const int d = idx / 6, f = idx % 6;
      float sn, cs; __sincosf(s_inT[d][j] * (float)(1 << f), &sn, &cs);
      s_inT[27 + idx][j]  = sn;
      s_inT[189 + idx][j] = cs;
    }
    __syncthreads();

    const int nrn = tid & 127;
    const int j0  = (tid >> 7) * 4;

    float a1[4];
    {
      const float bb = b1[nrn];
#pragma unroll
      for (int i = 0; i < 4; ++i) a1[i] = bb;
    }
    const float* w1p = W1 + nrn;
#pragma unroll 9
    for (int r = 0; r < 27; ++r) {          // feats: k = r
      const float wv = w1p[r * FC];
      const float4 v0 = *(const float4*)&s_inT[r][j0];
      a1[0] = fmaf(v0.x, wv, a1[0]); a1[1] = fmaf(v0.y, wv, a1[1]);
      a1[2] = fmaf(v0.z, wv, a1[2]); a1[3] = fmaf(v0.w, wv, a1[3]);
    }
#pragma unroll 8
    for (int r = 27; r < 351; ++r) {        // PE(feats): k = r + 3
      const float wv = w1p[(r + 3) * FC];
      const float4 v0 = *(const float4*)&s_inT[r][j0];
      a1[0] = fmaf(v0.x, wv, a1[0]); a1[1] = fmaf(v0.y, wv, a1[1]);
      a1[2] = fmaf(v0.z, wv, a1[2]); a1[3] = fmaf(v0.w, wv, a1[3]);
    }
#pragma unroll
    for (int r = 351; r < 390; ++r) {       // vd: k = r-324; PE(vd): k = r
      const int k = (r < 354) ? (r - 324) : r;
      const float wv = w1p[k * FC];
      const float4 v0 = *(const float4*)&s_inT[r][j0];
      a1[0] = fmaf(v0.x, wv, a1[0]); a1[1] = fmaf(v0.y, wv, a1[1]);
      a1[2] = fmaf(v0.z, wv, a1[2]); a1[3] = fmaf(v0.w, wv, a1[3]);
    }
#pragma unroll
    for (int i = 0; i < 4; ++i) s_hT[nrn][j0 + i] = fmaxf(a1[i], 0.0f);
    __syncthreads();

    float a2[4];
    {
      const float bb = b2[nrn];
#pragma unroll
      for (int i = 0; i < 4; ++i) a2[i] = bb;
    }
#pragma unroll 4
    for (int k = 0; k < FC; ++k) {
      const float wv = W2[k * FC + nrn];
      const float4 u0 = *(const float4*)&s_hT[k][j0];
      a2[0] = fmaf(u0.x, wv, a2[0]); a2[1] = fmaf(u0.y, wv, a2[1]);
      a2[2] = fmaf(u0.z, wv, a2[2]); a2[3] = fmaf(u0.w, wv, a2[3]);
    }
    float* s_h2 = &s_inT[0][0];  // reuse as [128][12]; inT reads done pre-barrier
#pragma unroll
    for (int i = 0; i < 4; ++i) s_h2[nrn * 12 + j0 + i] = fmaxf(a2[i], 0.0f);
    __syncthreads();

    if (tid < 3 * TILE) {
      const int j = tid / 3, c = tid - j * 3;
      if (s_vld[j] && s_jw[j] != 0.0f) {
        float a3 = b3[c];
#pragma unroll 8
        for (int k = 0; k < FC; ++k)
          a3 = fmaf(s_h2[k * 12 + j], W3[k * 3 + c], a3);
        const float rgb = 1.0f / (1.0f + __expf(-a3));
        atomicAdd(&out[s_rayid[j] * 3 + c], s_jw[j] * rgb);
      }
    }
    __syncthreads();
  }
}

extern "C" void kernel_launch(void* const* d_in, const int* in_sizes, int n_in,
                              void* d_out, int out_size, void* d_ws, size_t ws_size,
                              hipStream_t stream) {
  const float* rays_o = (const float*)d_in[0];
  const float* rays_d = (const float*)d_in[1];
  const float* dgrid  = (const float*)d_in[2];
  const float* agrid  = (const float*)d_in[3];
  const float* W1     = (const float*)d_in[4];
  const float* b1     = (const float*)d_in[5];
  const float* W2     = (const float*)d_in[6];
  const float* b2     = (const float*)d_in[7];
  const float* W3     = (const float*)d_in[8];
  const float* b3     = (const float*)d_in[9];
  float* out = (float*)d_out;

  char* ws = (char*)d_ws;
  float*         g_dir  = (float*)(ws);                         // 24 KB
  unsigned char* g_cnt8 = (unsigned char*)(ws + 24576);         // 2 KB
  float*         g_w    = (float*)(ws + 32768);                 // 384 KB
  unsigned char* g_sidx = (unsigned char*)(ws + 32768 + 393216);// 96 KB

  hipLaunchKernelGGL(k_prep, dim3(NRAYS / 4), dim3(256), 0, stream,
                     rays_o, rays_d, dgrid, W1, W2, W3, b1, b2, b3,
                     out, g_dir, g_cnt8, g_sidx, g_w);
  hipLaunchKernelGGL(k_items, dim3(NB2), dim3(256), 0, stream,
                     rays_o, g_dir, agrid, W1, W2, W3, b1, b2, b3,
                     g_cnt8, g_sidx, g_w, out);
}

// Round 14
// 58.501 us; speedup vs baseline: 6.0416x; 1.1281x over previous
//
#include <hip/hip_runtime.h>

#define NRAYS 2048
#define NS    128
#define G     128
#define FC    128
#define APPC  27
#define TILE  8
#define MAXP  48    // max in-bounds samples per ray (geometric bound ~24)
#define R1    351   // compact item rows: 27 feats + 162 sin + 162 cos; W1 row k = r<27 ? r : r+3

static __device__ __forceinline__ float tri_sample(const float* __restrict__ vol,
                                                   float gx, float gy, float gz) {
  int x0 = (int)gx; x0 = x0 < 0 ? 0 : (x0 > G - 2 ? G - 2 : x0);
  int y0 = (int)gy; y0 = y0 < 0 ? 0 : (y0 > G - 2 ? G - 2 : y0);
  int z0 = (int)gz; z0 = z0 < 0 ? 0 : (z0 > G - 2 ? G - 2 : z0);
  float fx = gx - (float)x0;
  float fy = gy - (float)y0;
  float fz = gz - (float)z0;
  const float* p = vol + ((z0 * G + y0) * G + x0);
  float v000 = p[0], v001 = p[1];
  float v010 = p[G], v011 = p[G + 1];
  const float* q = p + G * G;
  float v100 = q[0], v101 = q[1];
  float v110 = q[G], v111 = q[G + 1];
  float c00 = v000 + (v001 - v000) * fx;
  float c01 = v010 + (v011 - v010) * fx;
  float c10 = v100 + (v101 - v100) * fx;
  float c11 = v110 + (v111 - v110) * fx;
  float c0  = c00 + (c01 - c00) * fy;
  float c1  = c10 + (c11 - c10) * fy;
  return c0 + (c1 - c0) * fz;
}

// softplus(x) for x <= ~-5: log1p(e^x) = e^x - e^x^2/2; abs error < 1e-8
static __device__ __forceinline__ float sample_alpha(const float* __restrict__ dgrid,
                                                     float ox, float oy, float oz,
                                                     float dx, float dy, float dz,
                                                     int s, bool& inb) {
  const float t  = 2.0f + (4.0f / 127.0f) * (float)s;
  const float px = (ox + dx * t) * (2.0f / 3.0f);
  const float py = (oy + dy * t) * (2.0f / 3.0f);
  const float pz = (oz + dz * t) * (2.0f / 3.0f);
  inb = (fabsf(px) <= 1.0f) && (fabsf(py) <= 1.0f) && (fabsf(pz) <= 1.0f);
  float sf = 0.0f;
  if (inb)
    sf = tri_sample(dgrid, (px + 1.0f) * 63.5f, (py + 1.0f) * 63.5f, (pz + 1.0f) * 63.5f);
  const float y  = __expf(sf - 10.0f);
  const float sp = y - 0.5f * y * y;
  return 1.0f - __expf(-sp * 0.78125f);
}

// ---------------- K1: prep (blocks 0-511, wave/ray) || base (blocks 512-767, 8 rays each) ----------------
__global__ __launch_bounds__(256) void k_phase1(
    const float* __restrict__ rays_o, const float* __restrict__ rays_d,
    const float* __restrict__ dgrid,
    const float* __restrict__ W1, const float* __restrict__ W2,
    const float* __restrict__ W3, const float* __restrict__ b1,
    const float* __restrict__ b2, const float* __restrict__ b3,
    float* __restrict__ out, float* __restrict__ g_dir,
    float* __restrict__ g_woob, float* __restrict__ g_hbase,
    float* __restrict__ g_rgboob, unsigned char* __restrict__ g_cnt8,
    unsigned char* __restrict__ g_sidx, float* __restrict__ g_w) {
  const int bid = blockIdx.x;
  const int tid = threadIdx.x;

  if (bid < 512) {
    // ---- prep: one wave per ray; fixed per-ray slots, no atomics ----
    const int ray  = bid * 4 + (tid >> 6);
    const int lane = tid & 63;

    const float rdx = rays_d[ray * 3 + 0], rdy = rays_d[ray * 3 + 1], rdz = rays_d[ray * 3 + 2];
    const float inv = rsqrtf(rdx * rdx + rdy * rdy + rdz * rdz);
    const float dx = rdx * inv, dy = rdy * inv, dz = rdz * inv;
    const float ox = rays_o[ray * 3 + 0], oy = rays_o[ray * 3 + 1], oz = rays_o[ray * 3 + 2];
    if (lane == 0) {
      g_dir[ray * 3 + 0] = dx; g_dir[ray * 3 + 1] = dy; g_dir[ray * 3 + 2] = dz;
    }

    const int s0 = lane * 2, s1 = s0 + 1;
    bool in0, in1;
    const float al0 = sample_alpha(dgrid, ox, oy, oz, dx, dy, dz, s0, in0);
    const float al1 = sample_alpha(dgrid, ox, oy, oz, dx, dy, dz, s1, in1);

    const float p0 = 1.0f - al0 + 1e-10f;
    const float p1 = 1.0f - al1 + 1e-10f;
    float incl = p0 * p1;
#pragma unroll
    for (int off = 1; off < 64; off <<= 1) {
      float v = __shfl_up(incl, off);
      if (lane >= off) incl *= v;
    }
    float excl = __shfl_up(incl, 1);
    if (lane == 0) excl = 1.0f;
    const float w0 = al0 * excl;
    const float w1 = al1 * excl * p0;

    float acc  = w0 + w1;
    float woob = (in0 ? 0.0f : w0) + (in1 ? 0.0f : w1);
#pragma unroll
    for (int off = 32; off > 0; off >>= 1) {
      acc  += __shfl_xor(acc, off);
      woob += __shfl_xor(woob, off);
    }

    const unsigned long long m0 = __ballot(in0);
    const unsigned long long m1 = __ballot(in1);
    const int n_in = (int)__popcll(m0) + (int)__popcll(m1);

    if (lane == 0) {
      g_woob[ray] = woob;
      g_cnt8[ray] = (unsigned char)((n_in > MAXP) ? MAXP : n_in);
    }
    if (lane < 3) out[ray * 3 + lane] = 1.0f - acc;   // K2 atomically adds onto this

    const unsigned long long low = (1ull << lane) - 1ull;
    const int r0 = (int)__popcll(m0 & low) + (int)__popcll(m1 & low);
    if (in0 && r0 < MAXP) {
      g_sidx[ray * MAXP + r0] = (unsigned char)s0;
      g_w[ray * MAXP + r0]    = w0;
    }
    if (in1) {
      const int r1 = r0 + (in0 ? 1 : 0);
      if (r1 < MAXP) {
        g_sidx[ray * MAXP + r1] = (unsigned char)s1;
        g_w[ray * MAXP + r1]    = w1;
      }
    }
    return;
  }

  // ---- base: 8 rays per block (256 blocks) -> g_hbase + g_rgboob ----
  __shared__ float s_in[39][8];      // rows 0-2 vd; 3-20 sin(vd); 21-38 cos(vd)
  __shared__ float s_h1[FC][12];
  __shared__ float s_h2[FC][12];
  __shared__ float s_bc[FC], s_ps[FC];

  const int r0 = (bid - 512) * 8;
  if (tid < 24) {
    const int j = tid & 7, d = tid >> 3;
    const float rdx = rays_d[(r0 + j) * 3 + 0], rdy = rays_d[(r0 + j) * 3 + 1],
                rdz = rays_d[(r0 + j) * 3 + 2];
    const float inv = rsqrtf(rdx * rdx + rdy * rdy + rdz * rdz);
    s_in[d][j] = (d == 0) ? rdx * inv : ((d == 1) ? rdy * inv : rdz * inv);
  }
  {  // cos(0)-block column sums, two interleaved halves (no dep on s_in)
    const int nrn = tid & 127, h = tid >> 7;
    float v = 0.0f;
#pragma unroll 9
    for (int k = 192 + h; k < 354; k += 2) v += W1[k * FC + nrn];
    if (h) s_ps[nrn] = v; else s_bc[nrn] = v;
  }
  __syncthreads();
  for (int a = tid; a < 18 * 8; a += 256) {
    const int j = a & 7, idx = a >> 3, d = idx / 6, f = idx % 6;
    float sn, cs; __sincosf(s_in[d][j] * (float)(1 << f), &sn, &cs);
    s_in[3 + idx][j]  = sn;
    s_in[21 + idx][j] = cs;
  }
  __syncthreads();

  const int nrn = tid & 127;
  const int j0  = (tid >> 7) * 4;

  float a1[4];
  {
    const float bb = b1[nrn];
#pragma unroll
    for (int i = 0; i < 4; ++i) a1[i] = bb;
  }
#pragma unroll
  for (int r = 0; r < 39; ++r) {
    const int k = (r < 3) ? (27 + r) : (351 + r);
    const float wv = W1[k * FC + nrn];
    const float4 v0 = *(const float4*)&s_in[r][j0];
    a1[0] = fmaf(v0.x, wv, a1[0]); a1[1] = fmaf(v0.y, wv, a1[1]);
    a1[2] = fmaf(v0.z, wv, a1[2]); a1[3] = fmaf(v0.w, wv, a1[3]);
  }
  const float bcv = s_bc[nrn] + s_ps[nrn];
#pragma unroll
  for (int i = 0; i < 4; ++i) {
    g_hbase[(size_t)(r0 + j0 + i) * FC + nrn] = a1[i];
    s_h1[nrn][j0 + i] = fmaxf(a1[i] + bcv, 0.0f);
  }
  __syncthreads();

  float a2[4];
  {
    const float bb = b2[nrn];
#pragma unroll
    for (int i = 0; i < 4; ++i) a2[i] = bb;
  }
#pragma unroll 4
  for (int k = 0; k < FC; ++k) {
    const float wv = W2[k * FC + nrn];
    const float4 u0 = *(const float4*)&s_h1[k][j0];
    a2[0] = fmaf(u0.x, wv, a2[0]); a2[1] = fmaf(u0.y, wv, a2[1]);
    a2[2] = fmaf(u0.z, wv, a2[2]); a2[3] = fmaf(u0.w, wv, a2[3]);
  }
#pragma unroll
  for (int i = 0; i < 4; ++i) s_h2[nrn][j0 + i] = fmaxf(a2[i], 0.0f);
  __syncthreads();

  if (tid < 24) {
    const int j = tid / 3, c = tid - j * 3;
    float a3 = b3[c];
#pragma unroll 8
    for (int k = 0; k < FC; ++k)
      a3 = fmaf(s_h2[k][j], W3[k * 3 + c], a3);
    g_rgboob[(r0 + j) * 3 + c] = 1.0f / (1.0f + __expf(-a3));
  }
}

// ---------------- K2: per-block prefix over g_cnt8 + OOB composite + item MLP (TILE=8) ----------------
__global__ __launch_bounds__(256) void k_items(const float* __restrict__ rays_o,
                                               const float* __restrict__ g_dir,
                                               const float* __restrict__ agrid,
                                               const float* __restrict__ W1,
                                               const float* __restrict__ W2,
                                               const float* __restrict__ W3,
                                               const float* __restrict__ b2,
                                               const float* __restrict__ b3,
                                               const float* __restrict__ g_hbase,
                                               const float* __restrict__ g_woob,
                                               const float* __restrict__ g_rgboob,
                                               const unsigned char* __restrict__ g_cnt8,
                                               const unsigned char* __restrict__ g_sidx,
                                               const float* __restrict__ g_w,
                                               float* __restrict__ out) {
  const int tid = threadIdx.x;
  __shared__ int   s_pfx[NRAYS + 1];  // 8196 B, persists across tiles
  __shared__ int   s_wt[4];
  __shared__ float s_inT[R1][TILE];   // 11.2 KB; tail-reused as h2 [128][12]
  __shared__ float s_hT[FC][12];      // 6 KB
  __shared__ int   s_rayid[TILE];
  __shared__ float s_jw[TILE], s_gx[TILE], s_gy[TILE], s_gz[TILE];
  __shared__ int   s_vld[TILE];

  // ---- exclusive prefix sum of per-ray item counts (uchar, exact ints) ----
  {
    const int b0 = tid * 8;
    const uint2 cc = *(const uint2*)&g_cnt8[b0];
    int c8[8];
#pragma unroll
    for (int i = 0; i < 4; ++i) c8[i]     = (int)((cc.x >> (8 * i)) & 0xff);
#pragma unroll
    for (int i = 0; i < 4; ++i) c8[4 + i] = (int)((cc.y >> (8 * i)) & 0xff);
    int ex[8], run = 0;
#pragma unroll
    for (int i = 0; i < 8; ++i) { ex[i] = run; run += c8[i]; }
    int inclv = run;
    const int lane = tid & 63;
#pragma unroll
    for (int off = 1; off < 64; off <<= 1) {
      int v = __shfl_up(inclv, off);
      if (lane >= off) inclv += v;
    }
    if (lane == 63) s_wt[tid >> 6] = inclv;
    __syncthreads();
    int woff = 0;
    const int wq = tid >> 6;
    if (wq > 0) woff += s_wt[0];
    if (wq > 1) woff += s_wt[1];
    if (wq > 2) woff += s_wt[2];
    const int tbase = woff + inclv - run;
#pragma unroll
    for (int i = 0; i < 8; ++i) s_pfx[b0 + i] = tbase + ex[i];
    if (tid == 255) s_pfx[NRAYS] = tbase + run;
  }
  __syncthreads();
  const int total  = s_pfx[NRAYS];
  const int ntiles = 8 + ((total + TILE - 1) >> 3);

  for (int tile = blockIdx.x; tile < ntiles; tile += gridDim.x) {
    if (tile < 8) {   // OOB composite (block-uniform branch, no barriers inside)
      const int ray = tile * 256 + tid;
      const float wv = g_woob[ray];
#pragma unroll
      for (int c = 0; c < 3; ++c)
        atomicAdd(&out[ray * 3 + c], wv * g_rgboob[ray * 3 + c]);
      continue;
    }
    const int it = tile - 8;

    if (tid < TILE) {
      const int gi  = it * TILE + tid;
      const int vld = gi < total;
      int ray = 0, s = 0;
      float wj = 0.0f;
      if (vld) {
        int lo = 0, hi = NRAYS - 1;
        while (lo < hi) {
          const int mid = (lo + hi + 1) >> 1;
          if (s_pfx[mid] <= gi) lo = mid; else hi = mid - 1;
        }
        ray = lo;
        const int slot = gi - s_pfx[ray];
        s  = g_sidx[ray * MAXP + slot];
        wj = g_w[ray * MAXP + slot];
      }
      s_rayid[tid] = ray;
      s_vld[tid]   = vld;
      s_jw[tid]    = wj;
      const float dxx = g_dir[ray * 3 + 0], dyy = g_dir[ray * 3 + 1], dzz = g_dir[ray * 3 + 2];
      const float t = 2.0f + (4.0f / 127.0f) * (float)s;
      s_gx[tid] = ((rays_o[ray * 3 + 0] + dxx * t) * (2.0f / 3.0f) + 1.0f) * 63.5f;
      s_gy[tid] = ((rays_o[ray * 3 + 1] + dyy * t) * (2.0f / 3.0f) + 1.0f) * 63.5f;
      s_gz[tid] = ((rays_o[ray * 3 + 2] + dzz * t) * (2.0f / 3.0f) + 1.0f) * 63.5f;
    }
    __syncthreads();

    // fused gather + PE: thread (c,j) samples channel c then emits its 6 sin/cos pairs
    if (tid < APPC * TILE) {   // 216 threads
      const int j = tid & (TILE - 1), c = tid >> 3;
      const float v = s_vld[j]
          ? tri_sample(agrid + (size_t)c * G * G * G, s_gx[j], s_gy[j], s_gz[j])
          : 0.0f;
      s_inT[c][j] = v;
#pragma unroll
      for (int f = 0; f < 6; ++f) {
        float sn, cs; __sincosf(v * (float)(1 << f), &sn, &cs);
        s_inT[27 + c * 6 + f][j]  = sn;
        s_inT[189 + c * 6 + f][j] = cs;
      }
    }
    __syncthreads();

    const int nrn = tid & 127;
    const int j0  = (tid >> 7) * 4;

    float a1[4];
#pragma unroll
    for (int i = 0; i < 4; ++i)
      a1[i] = g_hbase[(size_t)s_rayid[j0 + i] * FC + nrn];

    const float* w1p = W1 + nrn;
#pragma unroll 9
    for (int r = 0; r < 27; ++r) {
      const float wv = w1p[r * FC];
      const float4 v0 = *(const float4*)&s_inT[r][j0];
      a1[0] = fmaf(v0.x, wv, a1[0]); a1[1] = fmaf(v0.y, wv, a1[1]);
      a1[2] = fmaf(v0.z, wv, a1[2]); a1[3] = fmaf(v0.w, wv, a1[3]);
    }
#pragma unroll 8
    for (int r = 27; r < R1; ++r) {
      const float wv = w1p[(r + 3) * FC];
      const float4 v0 = *(const float4*)&s_inT[r][j0];
      a1[0] = fmaf(v0.x, wv, a1[0]); a1[1] = fmaf(v0.y, wv, a1[1]);
      a1[2] = fmaf(v0.z, wv, a1[2]); a1[3] = fmaf(v0.w, wv, a1[3]);
    }
#pragma unroll
    for (int i = 0; i < 4; ++i) s_hT[nrn][j0 + i] = fmaxf(a1[i], 0.0f);
    __syncthreads();

    float a2[4];
    {
      const float bb = b2[nrn];
#pragma unroll
      for (int i = 0; i < 4; ++i) a2[i] = bb;
    }
#pragma unroll 4
    for (int k = 0; k < FC; ++k) {
      const float wv = W2[k * FC + nrn];
      const float4 u0 = *(const float4*)&s_hT[k][j0];
      a2[0] = fmaf(u0.x, wv, a2[0]); a2[1] = fmaf(u0.y, wv, a2[1]);
      a2[2] = fmaf(u0.z, wv, a2[2]); a2[3] = fmaf(u0.w, wv, a2[3]);
    }
    float* s_h2 = &s_inT[0][0];  // reuse as [128][12]; all s_inT reads finished pre-barrier
#pragma unroll
    for (int i = 0; i < 4; ++i) s_h2[nrn * 12 + j0 + i] = fmaxf(a2[i], 0.0f);
    __syncthreads();

    if (tid < 3 * TILE) {
      const int j = tid / 3, c = tid - j * 3;
      if (s_vld[j] && s_jw[j] != 0.0f) {
        float a3 = b3[c];
#pragma unroll 8
        for (int k = 0; k < FC; ++k)
          a3 = fmaf(s_h2[k * 12 + j], W3[k * 3 + c], a3);
        const float rgb = 1.0f / (1.0f + __expf(-a3));
        atomicAdd(&out[s_rayid[j] * 3 + c], s_jw[j] * rgb);
      }
    }
    __syncthreads();
  }
}

extern "C" void kernel_launch(void* const* d_in, const int* in_sizes, int n_in,
                              void* d_out, int out_size, void* d_ws, size_t ws_size,
                              hipStream_t stream) {
  const float* rays_o = (const float*)d_in[0];
  const float* rays_d = (const float*)d_in[1];
  const float* dgrid  = (const float*)d_in[2];
  const float* agrid  = (const float*)d_in[3];
  const float* W1     = (const float*)d_in[4];
  const float* b1     = (const float*)d_in[5];
  const float* W2     = (const float*)d_in[6];
  const float* b2     = (const float*)d_in[7];
  const float* W3     = (const float*)d_in[8];
  const float* b3     = (const float*)d_in[9];
  float* out = (float*)d_out;

  char* ws = (char*)d_ws;
  float*         g_dir    = (float*)(ws);                 // 24 KB
  float*         g_woob   = (float*)(ws + 24576);         // 8 KB
  float*         g_rgboob = (float*)(ws + 32768);         // 24 KB
  unsigned char* g_cnt8   = (unsigned char*)(ws + 57344); // 2 KB
  float*         g_hbase  = (float*)(ws + 65536);         // 1 MB
  float*         g_w      = (float*)(ws + 65536 + 1048576);                    // 384 KB
  unsigned char* g_sidx   = (unsigned char*)(ws + 65536 + 1048576 + 393216);   // 96 KB

  hipLaunchKernelGGL(k_phase1, dim3(768), dim3(256), 0, stream,
                     rays_o, rays_d, dgrid, W1, W2, W3, b1, b2, b3,
                     out, g_dir, g_woob, g_hbase, g_rgboob, g_cnt8, g_sidx, g_w);
  hipLaunchKernelGGL(k_items, dim3(768), dim3(256), 0, stream,
                     rays_o, g_dir, agrid, W1, W2, W3, b2, b3,
                     g_hbase, g_woob, g_rgboob, g_cnt8, g_sidx, g_w, out);
}